// Round 2
// baseline (1578.581 us; speedup 1.0000x reference)
//
#include <hip/hip_runtime.h>

// ---------------------------------------------------------------------------
// CustomTransformerEncoder (differential attention + GRU gate + FFN), MI355X
// All GEMMs: bf16 inputs, fp32 MFMA accumulate (mfma_f32_16x16x32_bf16),
// 128x128 tile, BK=32, global_load_lds width=16 staging (m97 structure).
// Workspace: 228 MiB via liveness aliasing (R1 128 MiB multi-role, cat1 64
// MiB, conn lives in d_out).
// ---------------------------------------------------------------------------

#define DEV __device__ __forceinline__

typedef unsigned short u16;
typedef __bf16 bf16x8 __attribute__((ext_vector_type(8)));
typedef float f32x4 __attribute__((ext_vector_type(4)));
typedef unsigned short us8 __attribute__((ext_vector_type(8)));
typedef unsigned short us4 __attribute__((ext_vector_type(4)));

#define LAMBDA0            0.35550906759096928f   // 0.8 - 0.6*exp(-0.3)
#define ONE_MINUS_LAMBDA0  0.6444909324090307f
#define QSCALE             0.17677669529663687f   // 32^-0.5

DEV float bf2f(u16 u) { union { unsigned u; float f; } x; x.u = ((unsigned)u) << 16; return x.f; }
DEV u16 f2bf(float f) {
  union { float f; unsigned u; } x; x.f = f;
  unsigned r = x.u + 0x7FFFu + ((x.u >> 16) & 1u);
  return (u16)(r >> 16);
}

DEV void gl_lds16(const void* g, void* l) {
  __builtin_amdgcn_global_load_lds((__attribute__((address_space(1))) void*)g,
                                   (__attribute__((address_space(3))) void*)l, 16, 0, 0);
}

// ---------------------------------------------------------------------------
// GEMM: C[m,n] = act( sum_k A[m,k] * W[n,k] + bias[n] )
// A: [M, *] bf16 row-major with leading dim lda; W: [N, K] bf16 (ld == K).
// ACT: 0 none, 1 relu, 2 sigmoid, 3 tanh.  OBF: 1 -> bf16 out, 0 -> f32 out.
// grid = (N/128, M/128), block = 256 (4 waves, 2x2, 64x64 each).
// ---------------------------------------------------------------------------
template <int ACT, int OBF>
__global__ __launch_bounds__(256)
void gemm_bt(const u16* __restrict__ A, int lda, const u16* __restrict__ W,
             const float* __restrict__ bias, void* __restrict__ outp,
             int ldo, int K)
{
  __shared__ u16 As[128 * 32];
  __shared__ u16 Bs[128 * 32];
  const int tid = threadIdx.x;
  const int lane = tid & 63, wave = tid >> 6;
  const int m0 = blockIdx.y * 128, n0 = blockIdx.x * 128;
  const int wm = (wave >> 1) * 64, wn = (wave & 1) * 64;

  f32x4 acc[4][4] = {};

  // staging: wave w covers tile rows [32w, 32w+32) via two 1KB chunks
  const int srow = wave * 32 + (lane >> 2);
  const int scol = (lane & 3) * 8;
  const u16* gA0 = A + (size_t)(m0 + srow) * lda + scol;
  const u16* gA1 = gA0 + (size_t)16 * lda;
  const u16* gB0 = W + (size_t)(n0 + srow) * K + scol;
  const u16* gB1 = gB0 + (size_t)16 * K;
  u16* lA0 = As + wave * 1024;  u16* lA1 = lA0 + 512;
  u16* lB0 = Bs + wave * 1024;  u16* lB1 = lB0 + 512;

  const int frow = lane & 15;
  const int fk = (lane >> 4) * 8;

  for (int k0 = 0; k0 < K; k0 += 32) {
    gl_lds16(gA0 + k0, lA0);
    gl_lds16(gA1 + k0, lA1);
    gl_lds16(gB0 + k0, lB0);
    gl_lds16(gB1 + k0, lB1);
    __syncthreads();
    bf16x8 af[4], bfr[4];
#pragma unroll
    for (int i = 0; i < 4; ++i) {
      af[i]  = *(const bf16x8*)&As[(wm + i * 16 + frow) * 32 + fk];
      bfr[i] = *(const bf16x8*)&Bs[(wn + i * 16 + frow) * 32 + fk];
    }
#pragma unroll
    for (int i = 0; i < 4; ++i)
#pragma unroll
      for (int j = 0; j < 4; ++j)
        acc[i][j] = __builtin_amdgcn_mfma_f32_16x16x32_bf16(af[i], bfr[j], acc[i][j], 0, 0, 0);
    __syncthreads();
  }

  const int ec = lane & 15;
  const int er = (lane >> 4) * 4;
#pragma unroll
  for (int j = 0; j < 4; ++j) {
    const int gc = n0 + wn + j * 16 + ec;
    const float bv = bias ? bias[gc] : 0.f;
#pragma unroll
    for (int i = 0; i < 4; ++i) {
      const int gr = m0 + wm + i * 16 + er;
#pragma unroll
      for (int t = 0; t < 4; ++t) {
        float v = acc[i][j][t] + bv;
        if (ACT == 1) v = fmaxf(v, 0.f);
        else if (ACT == 2) v = 1.f / (1.f + expf(-v));
        else if (ACT == 3) v = tanhf(v);
        if (OBF) ((u16*)outp)[(size_t)(gr + t) * ldo + gc] = f2bf(v);
        else     ((float*)outp)[(size_t)(gr + t) * ldo + gc] = v;
      }
    }
  }
}

// ---------------------------------------------------------------------------
// LayerNorm (f32 in -> bf16 out). One row (D=1024) per 256-thread block.
// ---------------------------------------------------------------------------
__global__ __launch_bounds__(256)
void ln_kernel(const float* __restrict__ in, const float* __restrict__ g,
               const float* __restrict__ b, u16* __restrict__ out)
{
  const int row = blockIdx.x, tid = threadIdx.x;
  const float4 x = ((const float4*)(in + (size_t)row * 1024))[tid];
  float s = x.x + x.y + x.z + x.w;
  float sq = x.x * x.x + x.y * x.y + x.z * x.z + x.w * x.w;
#pragma unroll
  for (int o = 32; o >= 1; o >>= 1) { s += __shfl_xor(s, o); sq += __shfl_xor(sq, o); }
  __shared__ float ls[4], lq[4];
  const int wave = tid >> 6;
  if ((tid & 63) == 0) { ls[wave] = s; lq[wave] = sq; }
  __syncthreads();
  s = ls[0] + ls[1] + ls[2] + ls[3];
  sq = lq[0] + lq[1] + lq[2] + lq[3];
  const float mean = s * (1.f / 1024.f);
  const float rstd = rsqrtf(sq * (1.f / 1024.f) - mean * mean + 1e-5f);
  const float4 gg = ((const float4*)g)[tid];
  const float4 bb = ((const float4*)b)[tid];
  us4 ov;
  ov[0] = f2bf((x.x - mean) * rstd * gg.x + bb.x);
  ov[1] = f2bf((x.y - mean) * rstd * gg.y + bb.y);
  ov[2] = f2bf((x.z - mean) * rstd * gg.z + bb.z);
  ov[3] = f2bf((x.w - mean) * rstd * gg.w + bb.w);
  *(us4*)(out + (size_t)row * 1024 + tid * 4) = ov;
}

// ---------------------------------------------------------------------------
// GRU combine + LayerNorm fused (one row per block):
//   conn = (1-z)*x + z*h ;  c = LN(conn)
// rzh: [16384][2048] f32, h in cols 0..1023, z in cols 1024..2047.
// writes: conn (f32, d_out), c (bf16 -> cat left, ld 2048),
//         bf16(conn) -> cat right (ld 2048).
// ---------------------------------------------------------------------------
__global__ __launch_bounds__(256)
void combine_ln_kernel(const float* __restrict__ x, const float* __restrict__ rzh,
                       const float* __restrict__ g, const float* __restrict__ b,
                       float* __restrict__ conn, u16* __restrict__ catbase)
{
  const int row = blockIdx.x, tid = threadIdx.x;
  const float4 xv = ((const float4*)(x + (size_t)row * 1024))[tid];
  const float4 hv = *(const float4*)(rzh + (size_t)row * 2048 + tid * 4);
  const float4 zv = *(const float4*)(rzh + (size_t)row * 2048 + 1024 + tid * 4);
  float4 cv;
  cv.x = (1.f - zv.x) * xv.x + zv.x * hv.x;
  cv.y = (1.f - zv.y) * xv.y + zv.y * hv.y;
  cv.z = (1.f - zv.z) * xv.z + zv.z * hv.z;
  cv.w = (1.f - zv.w) * xv.w + zv.w * hv.w;
  ((float4*)(conn + (size_t)row * 1024))[tid] = cv;
  us4 cb; cb[0] = f2bf(cv.x); cb[1] = f2bf(cv.y); cb[2] = f2bf(cv.z); cb[3] = f2bf(cv.w);
  *(us4*)(catbase + (size_t)row * 2048 + 1024 + tid * 4) = cb;

  float s = cv.x + cv.y + cv.z + cv.w;
  float sq = cv.x * cv.x + cv.y * cv.y + cv.z * cv.z + cv.w * cv.w;
#pragma unroll
  for (int o = 32; o >= 1; o >>= 1) { s += __shfl_xor(s, o); sq += __shfl_xor(sq, o); }
  __shared__ float ls[4], lq[4];
  const int wave = tid >> 6;
  if ((tid & 63) == 0) { ls[wave] = s; lq[wave] = sq; }
  __syncthreads();
  s = ls[0] + ls[1] + ls[2] + ls[3];
  sq = lq[0] + lq[1] + lq[2] + lq[3];
  const float mean = s * (1.f / 1024.f);
  const float rstd = rsqrtf(sq * (1.f / 1024.f) - mean * mean + 1e-5f);
  const float4 gg = ((const float4*)g)[tid];
  const float4 bb = ((const float4*)b)[tid];
  us4 ov;
  ov[0] = f2bf((cv.x - mean) * rstd * gg.x + bb.x);
  ov[1] = f2bf((cv.y - mean) * rstd * gg.y + bb.y);
  ov[2] = f2bf((cv.z - mean) * rstd * gg.z + bb.z);
  ov[3] = f2bf((cv.w - mean) * rstd * gg.w + bb.w);
  *(us4*)(catbase + (size_t)row * 2048 + tid * 4) = ov;
}

// final combine: out = (1-z)*x + z*h  (x may alias out; elementwise safe)
__global__ __launch_bounds__(256)
void combine2_kernel(const float* __restrict__ x, const float* __restrict__ rzh,
                     float* __restrict__ out)
{
  const int t = blockIdx.x * 256 + threadIdx.x;
  const int row = t >> 8;
  const int c4 = (t & 255) * 4;
  const float4 hv = *(const float4*)(rzh + (size_t)row * 2048 + c4);
  const float4 zv = *(const float4*)(rzh + (size_t)row * 2048 + 1024 + c4);
  const float4 xv = *(const float4*)(x + (size_t)row * 1024 + c4);
  float4 o;
  o.x = (1.f - zv.x) * xv.x + zv.x * hv.x;
  o.y = (1.f - zv.y) * xv.y + zv.y * hv.y;
  o.z = (1.f - zv.z) * xv.z + zv.z * hv.z;
  o.w = (1.f - zv.w) * xv.w + zv.w * hv.w;
  *(float4*)(out + (size_t)row * 1024 + c4) = o;
}

// rx = bf16(r * x) into cat right half (ld 2048); r = rzh cols 0..1023
__global__ __launch_bounds__(256)
void rx_kernel(const float* __restrict__ rzh, const float* __restrict__ x,
               u16* __restrict__ dst)
{
  const int t = blockIdx.x * 256 + threadIdx.x;
  const int row = t >> 8;
  const int c4 = (t & 255) * 4;
  const float4 rv = *(const float4*)(rzh + (size_t)row * 2048 + c4);
  const float4 xv = *(const float4*)(x + (size_t)row * 1024 + c4);
  us4 o;
  o[0] = f2bf(rv.x * xv.x); o[1] = f2bf(rv.y * xv.y);
  o[2] = f2bf(rv.z * xv.z); o[3] = f2bf(rv.w * xv.w);
  *(us4*)(dst + (size_t)row * 2048 + c4) = o;
}

// f32 -> bf16 2D convert with dst leading-dim (src contiguous [rows][2^cshift])
__global__ __launch_bounds__(256)
void cvt2d_kernel(const float* __restrict__ src, u16* __restrict__ dst,
                  int total4, int cshift, int ldd)
{
  const int t = blockIdx.x * 256 + threadIdx.x;
  if (t >= total4) return;
  const int idx = t * 4;
  const int r = idx >> cshift;
  const int c = idx & ((1 << cshift) - 1);
  const float4 v = *(const float4*)(src + (size_t)idx);
  us4 o; o[0] = f2bf(v.x); o[1] = f2bf(v.y); o[2] = f2bf(v.z); o[3] = f2bf(v.w);
  *(us4*)(dst + (size_t)r * ldd + c) = o;
}

__global__ __launch_bounds__(256)
void biasrz_kernel(const float* __restrict__ bg, float* __restrict__ brz)
{
  const int t = blockIdx.x * 256 + threadIdx.x;  // 2048
  brz[t] = (t < 1024) ? 0.f : -bg[t - 1024];
}

// sentinel: unmistakable absmax if workspace is too small
__global__ __launch_bounds__(256)
void sentinel_kernel(float* __restrict__ out, int n)
{
  const int t = blockIdx.x * 256 + threadIdx.x;
  if (t < n) out[t] = 1.0e9f;
}

// ---------------------------------------------------------------------------
// Per-token differential attention over the head axis.
// qkv: [16384][3072] bf16 (q|k|v). out: [16384][1024] bf16 (rmsnorm'ed, scaled).
// One wave per token; 4 tokens / 256-thread block.
// ---------------------------------------------------------------------------
__global__ __launch_bounds__(256)
void attn_kernel(const u16* __restrict__ qkv,
                 const float* __restrict__ lq1, const float* __restrict__ lq2,
                 const float* __restrict__ lk1, const float* __restrict__ lk2,
                 u16* __restrict__ out)
{
  __shared__ float k_s[4][32][36];
  __shared__ float att_s[4][32][33];
  const int wave = threadIdx.x >> 6, lane = threadIdx.x & 63;
  const int tok = blockIdx.x * 4 + wave;
  const u16* qrow = qkv + (size_t)tok * 3072;
  const u16* krow = qrow + 1024;
  const u16* vrow = qrow + 2048;

  // stage K, deinterleaved: k[(ki*16+h)][d] = krow[h*64 + d*2 + ki]
  {
    us8 a = *(const us8*)(krow + lane * 16);
    us8 b = *(const us8*)(krow + lane * 16 + 8);
#pragma unroll
    for (int j = 0; j < 16; ++j) {
      int e = lane * 16 + j;
      u16 usv = (j < 8) ? a[j] : b[j - 8];
      int h = e >> 6, r = e & 63;
      k_s[wave][(r & 1) * 16 + h][r >> 1] = bf2f(usv);
    }
  }
  // q row a = lane&31 into registers (scaled): q[a][d] = qrow[h*64 + d*2 + qi]
  float qr[32];
  {
    const int a = lane & 31, h = a & 15, qi = a >> 4;
#pragma unroll
    for (int s = 0; s < 8; ++s) {
      us8 v8 = *(const us8*)(qrow + h * 64 + s * 8);
#pragma unroll
      for (int u = 0; u < 4; ++u) qr[s * 4 + u] = bf2f(v8[2 * u + qi]) * QSCALE;
    }
  }
  // lambda (scalar)
  float lam;
  {
    const int dd = lane & 31;
    float p1 = lq1[dd] * lk1[dd], p2 = lq2[dd] * lk2[dd];
#pragma unroll
    for (int o = 16; o >= 1; o >>= 1) { p1 += __shfl_xor(p1, o); p2 += __shfl_xor(p2, o); }
    lam = expf(p1) - expf(p2) + LAMBDA0;
  }
  __syncthreads();

  // scores: lane owns row a for cols [bb, bb+16)
  const int a = lane & 31, bb = (lane >> 5) * 16;
  float av[16];
#pragma unroll
  for (int bi = 0; bi < 16; ++bi) {
    const float4* kk = (const float4*)&k_s[wave][bb + bi][0];
    float s = 0.f;
#pragma unroll
    for (int d4 = 0; d4 < 8; ++d4) {
      float4 kv = kk[d4];
      s += qr[d4 * 4 + 0] * kv.x + qr[d4 * 4 + 1] * kv.y +
           qr[d4 * 4 + 2] * kv.z + qr[d4 * 4 + 3] * kv.w;
    }
    av[bi] = s;
  }
  // softmax across the 32-wide row (2 lanes per row)
  float mx = av[0];
#pragma unroll
  for (int i = 1; i < 16; ++i) mx = fmaxf(mx, av[i]);
  mx = fmaxf(mx, __shfl_xor(mx, 32));
  float se = 0.f;
#pragma unroll
  for (int i = 0; i < 16; ++i) { av[i] = expf(av[i] - mx); se += av[i]; }
  se += __shfl_xor(se, 32);
  const float inv = 1.f / se;
#pragma unroll
  for (int i = 0; i < 16; ++i) att_s[wave][a][bb + i] = av[i] * inv;
  __syncthreads();

  // PV: lane owns out row a2 = lane>>2, cols [jb, jb+16)
  const int a2 = lane >> 2, jb = (lane & 3) * 16;
  float o[16];
#pragma unroll
  for (int j = 0; j < 16; ++j) o[j] = 0.f;
#pragma unroll
  for (int h = 0; h < 16; ++h) {
    const float dc = att_s[wave][a2][h] - lam * att_s[wave][16 + a2][16 + h];
    const u16* vv = vrow + h * 64 + jb;
    us8 v0 = *(const us8*)vv;
    us8 v1 = *(const us8*)(vv + 8);
#pragma unroll
    for (int j = 0; j < 8; ++j) { o[j] += dc * bf2f(v0[j]); o[8 + j] += dc * bf2f(v1[j]); }
  }
  // rmsnorm over 64 (4-lane group) + (1-lambda_init)
  float ss = 0.f;
#pragma unroll
  for (int j = 0; j < 16; ++j) ss += o[j] * o[j];
  ss += __shfl_xor(ss, 1);
  ss += __shfl_xor(ss, 2);
  const float sc = rsqrtf(ss * (1.f / 64.f) + 1e-5f) * ONE_MINUS_LAMBDA0;
  us8 r0, r1;
#pragma unroll
  for (int j = 0; j < 8; ++j) { r0[j] = f2bf(o[j] * sc); r1[j] = f2bf(o[8 + j] * sc); }
  u16* op = out + (size_t)tok * 1024 + a2 * 64 + jb;
  *(us8*)op = r0;
  *(us8*)(op + 8) = r1;
}

// ---------------------------------------------------------------------------
// Workspace layout (bytes), 228 MiB total. Liveness-based aliasing:
//  R1 (128 MiB): qkv bf16 [16384][3072] + {s, attn_out} bf16 at +96MiB
//                -> rzh f32 [16384][2048] (z cols 1024.., h overwrites r cols)
//                -> f1 bf16 [16384][4096] -> rzh2 f32
//  CAT (64 MiB): [y|x] -> [y|r*x] -> [c|conn_bf] -> [y2|conn_bf] -> [y2|r*conn]
//  conn f32 lives in d_out (combine2 updates it in place).
// ---------------------------------------------------------------------------
enum : size_t {
  OFF_WQKV = 0,
  OFF_WO   = OFF_WQKV + (size_t)3072 * 1024 * 2,
  OFF_WRZ  = OFF_WO   + (size_t)1024 * 1024 * 2,
  OFF_WG   = OFF_WRZ  + (size_t)2048 * 2048 * 2,
  OFF_W1   = OFF_WG   + (size_t)1024 * 2048 * 2,
  OFF_W2   = OFF_W1   + (size_t)4096 * 1024 * 2,
  OFF_BRZ  = OFF_W2   + (size_t)1024 * 4096 * 2,
  OFF_R1   = OFF_BRZ  + (size_t)2048 * 4,
  OFF_CAT  = OFF_R1   + (size_t)134217728,
  WS_NEED  = OFF_CAT  + (size_t)16384 * 2048 * 2
};

extern "C" void kernel_launch(void* const* d_in, const int* in_sizes, int n_in,
                              void* d_out, int out_size, void* d_ws, size_t ws_size,
                              hipStream_t stream)
{
  (void)in_sizes; (void)n_in;
  if (ws_size < WS_NEED) {   // unmistakable failure signature (absmax ~1e9)
    sentinel_kernel<<<(out_size + 255) / 256, 256, 0, stream>>>((float*)d_out, out_size);
    return;
  }

  const float* src  = (const float*)d_in[0];
  const float* Wq   = (const float*)d_in[1];
  const float* Wk   = (const float*)d_in[2];
  const float* Wv   = (const float*)d_in[3];
  const float* Wo   = (const float*)d_in[4];
  const float* bo   = (const float*)d_in[5];
  const float* lq1  = (const float*)d_in[6];
  const float* lq2  = (const float*)d_in[7];
  const float* lk1  = (const float*)d_in[8];
  const float* lk2  = (const float*)d_in[9];
  const float* ln1g = (const float*)d_in[10];
  const float* ln1b = (const float*)d_in[11];
  const float* ln2g = (const float*)d_in[12];
  const float* ln2b = (const float*)d_in[13];
  const float* W1   = (const float*)d_in[14];
  const float* b1   = (const float*)d_in[15];
  const float* W2   = (const float*)d_in[16];
  const float* b2   = (const float*)d_in[17];
  const float* Wr   = (const float*)d_in[18];
  const float* Ur   = (const float*)d_in[19];
  const float* Wz   = (const float*)d_in[20];
  const float* Uz   = (const float*)d_in[21];
  const float* Wg   = (const float*)d_in[22];
  const float* Ug   = (const float*)d_in[23];
  const float* bg   = (const float*)d_in[24];

  char* ws = (char*)d_ws;
  u16*   wqkv = (u16*)(ws + OFF_WQKV);
  u16*   wo_b = (u16*)(ws + OFF_WO);
  u16*   wrz  = (u16*)(ws + OFF_WRZ);
  u16*   wgc  = (u16*)(ws + OFF_WG);
  u16*   w1b  = (u16*)(ws + OFF_W1);
  u16*   w2b  = (u16*)(ws + OFF_W2);
  float* brz  = (float*)(ws + OFF_BRZ);
  u16*   r1u  = (u16*)(ws + OFF_R1);                 // qkv bf16 / f1 bf16
  u16*   sbuf = (u16*)(ws + OFF_R1 + 100663296);     // s / attn_out (R1+96MiB)
  float* rzh  = (float*)(ws + OFF_R1);               // rz/h f32 (aliases r1u)
  u16*   cat  = (u16*)(ws + OFF_CAT);                // [left | right], ld 2048
  float* conn = (float*)d_out;                       // conn lives in d_out

  auto cvt = [&](const float* s, u16* dst, int rows, int cshift, int ldd) {
    int total4 = (rows << cshift) >> 2;
    cvt2d_kernel<<<(total4 + 255) / 256, 256, 0, stream>>>(s, dst, total4, cshift, ldd);
  };

  // ---- weight prep (bf16, concatenated layouts) ----
  cvt(Wq, wqkv,                     1024, 10, 1024);
  cvt(Wk, wqkv + 1024 * 1024,       1024, 10, 1024);
  cvt(Wv, wqkv + 2 * 1024 * 1024,   1024, 10, 1024);
  cvt(Wo, wo_b,                     1024, 10, 1024);
  cvt(Wr, wrz,                      1024, 10, 2048);
  cvt(Ur, wrz + 1024,               1024, 10, 2048);
  cvt(Wz, wrz + 2048 * 1024,        1024, 10, 2048);
  cvt(Uz, wrz + 2048 * 1024 + 1024, 1024, 10, 2048);
  cvt(Wg, wgc,                      1024, 10, 2048);
  cvt(Ug, wgc + 1024,               1024, 10, 2048);
  cvt(W1, w1b,                      4096, 10, 1024);
  cvt(W2, w2b,                      1024, 12, 4096);
  cvt(src, cat + 1024,             16384, 10, 2048);   // x half of cat for GRU1
  biasrz_kernel<<<8, 256, 0, stream>>>(bg, brz);

  // ---- s = LN1(src) -> R1+96MiB ----
  ln_kernel<<<16384, 256, 0, stream>>>(src, ln1g, ln1b, sbuf);

  // ---- QKV fused GEMM -> R1[0:96MiB] [16384][3072] bf16 ----
  gemm_bt<0, 1><<<dim3(24, 128), 256, 0, stream>>>(sbuf, 1024, wqkv, nullptr, r1u, 3072, 1024);

  // ---- per-token differential attention -> R1+96MiB (over s, now dead) ----
  attn_kernel<<<4096, 256, 0, stream>>>(r1u, lq1, lq2, lk1, lk2, sbuf);

  // ---- y = relu(attn_out @ Wo.T + bo) -> cat left ----
  gemm_bt<1, 1><<<dim3(8, 128), 256, 0, stream>>>(sbuf, 1024, wo_b, bo, cat, 2048, 1024);

  // ---- GRU1 ----
  // [r|z] = sigmoid([y|x] @ [Wr|Ur;Wz|Uz].T + [0|-bg]) -> rzh f32 (qkv dead)
  gemm_bt<2, 0><<<dim3(16, 128), 256, 0, stream>>>(cat, 2048, wrz, brz, rzh, 2048, 2048);
  rx_kernel<<<16384, 256, 0, stream>>>(rzh, src, cat + 1024);            // r*x
  // h = tanh([y|r*x] @ [Wg|Ug].T) -> rzh cols 0..1023 (over r, now dead)
  gemm_bt<3, 0><<<dim3(8, 128), 256, 0, stream>>>(cat, 2048, wgc, nullptr, rzh, 2048, 2048);
  // conn = (1-z)src + z*h -> d_out ; c = LN2(conn) -> cat left ; conn_bf -> cat right
  combine_ln_kernel<<<16384, 256, 0, stream>>>(src, rzh, ln2g, ln2b, conn, cat);

  // ---- FFN: f1 = relu(c@W1.T+b1) -> R1 (rzh dead); y2 = relu(f1@W2.T+b2) -> cat left
  gemm_bt<1, 1><<<dim3(32, 128), 256, 0, stream>>>(cat, 2048, w1b, b1, r1u, 4096, 1024);
  gemm_bt<1, 1><<<dim3(8, 128), 256, 0, stream>>>(r1u, 4096, w2b, b2, cat, 2048, 4096);

  // ---- GRU2 ----
  gemm_bt<2, 0><<<dim3(16, 128), 256, 0, stream>>>(cat, 2048, wrz, brz, rzh, 2048, 2048);
  rx_kernel<<<16384, 256, 0, stream>>>(rzh, conn, cat + 1024);           // r*conn
  gemm_bt<3, 0><<<dim3(8, 128), 256, 0, stream>>>(cat, 2048, wgc, nullptr, rzh, 2048, 2048);
  combine2_kernel<<<16384, 256, 0, stream>>>(conn, rzh, (float*)d_out);
}

// Round 3
// 1317.636 us; speedup vs baseline: 1.1980x; 1.1980x over previous
//
#include <hip/hip_runtime.h>

// ---------------------------------------------------------------------------
// CustomTransformerEncoder (differential attention + GRU gate + FFN), MI355X
// GEMMs: 256x256 tile, BK=64, 8 waves (2x4), 8-phase-style schedule with
// counted vmcnt (T3+T4), LDS XOR swizzle slot^=row&7 (T2), setprio (T5),
// XCD-aware block swizzle (T1). bf16 in, fp32 MFMA accumulate.
// Race-freedom argument (blind-bench safe):
//  - quadrant q of a K-tile consumes A rows [64q,64q+64) ONLY in phase q;
//    B rows consumed only in phase 0.
//  - stage targets: p0/p1 -> A(t+1) into opposite buffer (last read ended
//    at tile t-1's final barrier); p2/p3 -> B(t+2) into current-parity B
//    buffer (read finished at phase-0's closing barrier). Every LDS write
//    is issued >=1 barrier after the last read of its destination.
//  - reads of staged data are protected by vmcnt(8)@p1 / vmcnt(6)@p3
//    placed BEFORE the phase-closing barrier, so all waves' loads are
//    forced before any wave reads them. Tail tiles clamp (not skip) stage
//    sources so vmcnt counts stay exact.
//  - barriers are asm volatile s_barrier with "memory" clobber: compiler
//    memory fence WITHOUT the vmcnt(0) drain of __syncthreads.
// ---------------------------------------------------------------------------

#define DEV __device__ __forceinline__

typedef unsigned short u16;
typedef __bf16 bf16x8 __attribute__((ext_vector_type(8)));
typedef float f32x4 __attribute__((ext_vector_type(4)));
typedef unsigned short us8 __attribute__((ext_vector_type(8)));
typedef unsigned short us4 __attribute__((ext_vector_type(4)));

#define LAMBDA0            0.35550906759096928f   // 0.8 - 0.6*exp(-0.3)
#define ONE_MINUS_LAMBDA0  0.6444909324090307f
#define QSCALE             0.17677669529663687f   // 32^-0.5

DEV float bf2f(u16 u) { union { unsigned u; float f; } x; x.u = ((unsigned)u) << 16; return x.f; }
DEV u16 f2bf(float f) {
  union { float f; unsigned u; } x; x.f = f;
  unsigned r = x.u + 0x7FFFu + ((x.u >> 16) & 1u);
  return (u16)(r >> 16);
}

DEV void gl_lds16(const void* g, void* l) {
  __builtin_amdgcn_global_load_lds((__attribute__((address_space(1))) void*)g,
                                   (__attribute__((address_space(3))) void*)l, 16, 0, 0);
}

#define MF(a, b, c) __builtin_amdgcn_mfma_f32_16x16x32_bf16(a, b, c, 0, 0, 0)
#define BARM() asm volatile("s_barrier" ::: "memory")

// stage one half-tile (128 rows x 64 cols bf16) with inverse-swizzled global
// source and LINEAR LDS dest (global_load_lds writes base + lane*16).
// LDS swizzle: 16B slot s of row r holds global slot s ^ (r&7).
DEV void stage_half_f(const u16* __restrict__ g, int ld, int rowbase, int k0,
                      u16* lds, int bufoff /*u16*/, int h, int wave, int lane)
{
  const int rr = lane >> 3;                       // row within 8-row group
  const int sc = ((lane & 7) ^ rr) * 8;           // inverse-swizzled col (elems)
  const u16* gs = g + (size_t)(rowbase + h * 128 + wave * 16 + rr) * ld + (k0 + sc);
  u16* l = lds + bufoff + h * 8192 + wave * 1024; // wave-uniform dest
  gl_lds16(gs, l);
  gl_lds16(gs + (size_t)8 * ld, l + 512);
}

// ---------------------------------------------------------------------------
// GEMM: C[m,n] = act( sum_k A[m,k] * W[n,k] + bias[n] )
// A: [M,*] bf16 row-major lda; W: [N,K] bf16 (ld==K). Requires M%256==0,
// N%256==0, K%64==0, K>=128, grid=(N/256, M/256) with grid.x*grid.y % 8 == 0.
// ACT: 0 none, 1 relu, 2 sigmoid, 3 tanh. OBF: 1 bf16 out, 0 f32 out.
// ---------------------------------------------------------------------------
template <int ACT, int OBF>
__global__ __launch_bounds__(512, 2)
void gemm256(const u16* __restrict__ A, int lda, const u16* __restrict__ W,
             const float* __restrict__ bias, void* __restrict__ outp,
             int ldo, int K)
{
  __shared__ u16 As[32768];   // [2 buf][256 rows][64 cols]
  __shared__ u16 Bs[32768];

  const int tid = threadIdx.x;
  const int lane = tid & 63, wave = tid >> 6;
  const int wr = wave >> 2, wc = wave & 3;
  const int frow = lane & 15, fx = lane >> 4, s7 = lane & 7;

  // T1: XCD-aware bijective swizzle (nwg % 8 == 0 for all launches here)
  const int gx = gridDim.x;
  const int nwg = gx * gridDim.y;
  const int lin = blockIdx.y * gx + blockIdx.x;
  const int logical = (lin & 7) * (nwg >> 3) + (lin >> 3);
  const int m0 = (logical / gx) * 256;
  const int n0 = (logical % gx) * 256;

  const int NT = K >> 6;
  const int aoff = (wr * 32 + frow) * 64;   // u16, within A tile
  const int boff = (wc * 64 + frow) * 64;   // u16, within B tile
  const int swA0 = (fx ^ s7) * 8;           // ks=0 swizzled slot offset
  const int swA1 = ((4 + fx) ^ s7) * 8;     // ks=1

  f32x4 acc[8][4] = {};
  bf16x8 bfr[4][2];

  // prologue: B0h0, B0h1, A0h0, A0h1, B1h0, B1h1 -> vmcnt(6) -> barrier
  stage_half_f(W, K, n0, 0, Bs, 0, 0, wave, lane);
  stage_half_f(W, K, n0, 0, Bs, 0, 1, wave, lane);
  stage_half_f(A, lda, m0, 0, As, 0, 0, wave, lane);
  stage_half_f(A, lda, m0, 0, As, 0, 1, wave, lane);
  stage_half_f(W, K, n0, 64, Bs, 16384, 0, wave, lane);
  stage_half_f(W, K, n0, 64, Bs, 16384, 1, wave, lane);
  asm volatile("s_waitcnt vmcnt(6)" ::: "memory");
  BARM();

#define PH(q, STG, TAILW)                                                     \
  {                                                                           \
    bf16x8 a00 = *(const bf16x8*)(As + aB + 4096 * (q) + swA0);               \
    bf16x8 a01 = *(const bf16x8*)(As + aB + 4096 * (q) + swA1);               \
    bf16x8 a10 = *(const bf16x8*)(As + aB + 4096 * (q) + 1024 + swA0);        \
    bf16x8 a11 = *(const bf16x8*)(As + aB + 4096 * (q) + 1024 + swA1);        \
    STG;                                                                      \
    BARM();                                                                   \
    __builtin_amdgcn_s_setprio(1);                                            \
    acc[2*(q)  ][0] = MF(a00, bfr[0][0], acc[2*(q)  ][0]);                    \
    acc[2*(q)  ][1] = MF(a00, bfr[1][0], acc[2*(q)  ][1]);                    \
    acc[2*(q)  ][2] = MF(a00, bfr[2][0], acc[2*(q)  ][2]);                    \
    acc[2*(q)  ][3] = MF(a00, bfr[3][0], acc[2*(q)  ][3]);                    \
    acc[2*(q)+1][0] = MF(a10, bfr[0][0], acc[2*(q)+1][0]);                    \
    acc[2*(q)+1][1] = MF(a10, bfr[1][0], acc[2*(q)+1][1]);                    \
    acc[2*(q)+1][2] = MF(a10, bfr[2][0], acc[2*(q)+1][2]);                    \
    acc[2*(q)+1][3] = MF(a10, bfr[3][0], acc[2*(q)+1][3]);                    \
    acc[2*(q)  ][0] = MF(a01, bfr[0][1], acc[2*(q)  ][0]);                    \
    acc[2*(q)  ][1] = MF(a01, bfr[1][1], acc[2*(q)  ][1]);                    \
    acc[2*(q)  ][2] = MF(a01, bfr[2][1], acc[2*(q)  ][2]);                    \
    acc[2*(q)  ][3] = MF(a01, bfr[3][1], acc[2*(q)  ][3]);                    \
    acc[2*(q)+1][0] = MF(a11, bfr[0][1], acc[2*(q)+1][0]);                    \
    acc[2*(q)+1][1] = MF(a11, bfr[1][1], acc[2*(q)+1][1]);                    \
    acc[2*(q)+1][2] = MF(a11, bfr[2][1], acc[2*(q)+1][2]);                    \
    acc[2*(q)+1][3] = MF(a11, bfr[3][1], acc[2*(q)+1][3]);                    \
    __builtin_amdgcn_s_setprio(0);                                            \
    TAILW;                                                                    \
    BARM();                                                                   \
  }

  for (int t = 0; t < NT; ++t) {
    const int cb = (t & 1) * 16384;          // current buffer (u16 offset)
    const int ob = 16384 - cb;               // opposite buffer
    const int kA = ((t + 1 < NT) ? t + 1 : NT - 1) * 64;  // clamp, keep counts
    const int kB = ((t + 2 < NT) ? t + 2 : NT - 1) * 64;
    const int aB = cb + aoff;
    const int bB = cb + boff;
    // phase 0: B frags (held all 4 phases) + A quadrant 0; stage A(t+1)h0
#pragma unroll
    for (int n = 0; n < 4; ++n) {
      bfr[n][0] = *(const bf16x8*)(Bs + bB + n * 1024 + swA0);
      bfr[n][1] = *(const bf16x8*)(Bs + bB + n * 1024 + swA1);
    }
    PH(0, stage_half_f(A, lda, m0, kA, As, ob, 0, wave, lane), (void)0);
    PH(1, stage_half_f(A, lda, m0, kA, As, ob, 1, wave, lane),
       asm volatile("s_waitcnt vmcnt(8)" ::: "memory"));
    PH(2, stage_half_f(W, K, n0, kB, Bs, cb, 0, wave, lane), (void)0);
    PH(3, stage_half_f(W, K, n0, kB, Bs, cb, 1, wave, lane),
       asm volatile("s_waitcnt vmcnt(6)" ::: "memory"));
  }
#undef PH

  // epilogue
  const int er = fx * 4;
#pragma unroll
  for (int q = 0; q < 4; ++q)
#pragma unroll
    for (int j = 0; j < 2; ++j) {
      const int grb = m0 + 64 * q + wr * 32 + j * 16 + er;
#pragma unroll
      for (int n = 0; n < 4; ++n) {
        const int gc = n0 + wc * 64 + n * 16 + frow;
        const float bv = bias ? bias[gc] : 0.f;
#pragma unroll
        for (int tt = 0; tt < 4; ++tt) {
          float v = acc[2 * q + j][n][tt] + bv;
          if (ACT == 1) v = fmaxf(v, 0.f);
          else if (ACT == 2) v = 1.f / (1.f + expf(-v));
          else if (ACT == 3) v = tanhf(v);
          if (OBF) ((u16*)outp)[(size_t)(grb + tt) * ldo + gc] = f2bf(v);
          else     ((float*)outp)[(size_t)(grb + tt) * ldo + gc] = v;
        }
      }
    }
}

// ---------------------------------------------------------------------------
// LayerNorm (f32 in -> bf16 out). One row (D=1024) per 256-thread block.
// ---------------------------------------------------------------------------
__global__ __launch_bounds__(256)
void ln_kernel(const float* __restrict__ in, const float* __restrict__ g,
               const float* __restrict__ b, u16* __restrict__ out)
{
  const int row = blockIdx.x, tid = threadIdx.x;
  const float4 x = ((const float4*)(in + (size_t)row * 1024))[tid];
  float s = x.x + x.y + x.z + x.w;
  float sq = x.x * x.x + x.y * x.y + x.z * x.z + x.w * x.w;
#pragma unroll
  for (int o = 32; o >= 1; o >>= 1) { s += __shfl_xor(s, o); sq += __shfl_xor(sq, o); }
  __shared__ float ls[4], lq[4];
  const int wave = tid >> 6;
  if ((tid & 63) == 0) { ls[wave] = s; lq[wave] = sq; }
  __syncthreads();
  s = ls[0] + ls[1] + ls[2] + ls[3];
  sq = lq[0] + lq[1] + lq[2] + lq[3];
  const float mean = s * (1.f / 1024.f);
  const float rstd = rsqrtf(sq * (1.f / 1024.f) - mean * mean + 1e-5f);
  const float4 gg = ((const float4*)g)[tid];
  const float4 bb = ((const float4*)b)[tid];
  us4 ov;
  ov[0] = f2bf((x.x - mean) * rstd * gg.x + bb.x);
  ov[1] = f2bf((x.y - mean) * rstd * gg.y + bb.y);
  ov[2] = f2bf((x.z - mean) * rstd * gg.z + bb.z);
  ov[3] = f2bf((x.w - mean) * rstd * gg.w + bb.w);
  *(us4*)(out + (size_t)row * 1024 + tid * 4) = ov;
}

// ---------------------------------------------------------------------------
// GRU combine + LayerNorm fused (one row per block):
//   conn = (1-z)*x + z*h ;  c = LN(conn)
// rzh: [16384][2048] f32, h in cols 0..1023, z in cols 1024..2047.
// ---------------------------------------------------------------------------
__global__ __launch_bounds__(256)
void combine_ln_kernel(const float* __restrict__ x, const float* __restrict__ rzh,
                       const float* __restrict__ g, const float* __restrict__ b,
                       float* __restrict__ conn, u16* __restrict__ catbase)
{
  const int row = blockIdx.x, tid = threadIdx.x;
  const float4 xv = ((const float4*)(x + (size_t)row * 1024))[tid];
  const float4 hv = *(const float4*)(rzh + (size_t)row * 2048 + tid * 4);
  const float4 zv = *(const float4*)(rzh + (size_t)row * 2048 + 1024 + tid * 4);
  float4 cv;
  cv.x = (1.f - zv.x) * xv.x + zv.x * hv.x;
  cv.y = (1.f - zv.y) * xv.y + zv.y * hv.y;
  cv.z = (1.f - zv.z) * xv.z + zv.z * hv.z;
  cv.w = (1.f - zv.w) * xv.w + zv.w * hv.w;
  ((float4*)(conn + (size_t)row * 1024))[tid] = cv;
  us4 cb; cb[0] = f2bf(cv.x); cb[1] = f2bf(cv.y); cb[2] = f2bf(cv.z); cb[3] = f2bf(cv.w);
  *(us4*)(catbase + (size_t)row * 2048 + 1024 + tid * 4) = cb;

  float s = cv.x + cv.y + cv.z + cv.w;
  float sq = cv.x * cv.x + cv.y * cv.y + cv.z * cv.z + cv.w * cv.w;
#pragma unroll
  for (int o = 32; o >= 1; o >>= 1) { s += __shfl_xor(s, o); sq += __shfl_xor(sq, o); }
  __shared__ float ls[4], lq[4];
  const int wave = tid >> 6;
  if ((tid & 63) == 0) { ls[wave] = s; lq[wave] = sq; }
  __syncthreads();
  s = ls[0] + ls[1] + ls[2] + ls[3];
  sq = lq[0] + lq[1] + lq[2] + lq[3];
  const float mean = s * (1.f / 1024.f);
  const float rstd = rsqrtf(sq * (1.f / 1024.f) - mean * mean + 1e-5f);
  const float4 gg = ((const float4*)g)[tid];
  const float4 bb = ((const float4*)b)[tid];
  us4 ov;
  ov[0] = f2bf((cv.x - mean) * rstd * gg.x + bb.x);
  ov[1] = f2bf((cv.y - mean) * rstd * gg.y + bb.y);
  ov[2] = f2bf((cv.z - mean) * rstd * gg.z + bb.z);
  ov[3] = f2bf((cv.w - mean) * rstd * gg.w + bb.w);
  *(us4*)(catbase + (size_t)row * 2048 + tid * 4) = ov;
}

// final combine: out = (1-z)*x + z*h  (x may alias out; elementwise safe)
__global__ __launch_bounds__(256)
void combine2_kernel(const float* __restrict__ x, const float* __restrict__ rzh,
                     float* __restrict__ out)
{
  const int t = blockIdx.x * 256 + threadIdx.x;
  const int row = t >> 8;
  const int c4 = (t & 255) * 4;
  const float4 hv = *(const float4*)(rzh + (size_t)row * 2048 + c4);
  const float4 zv = *(const float4*)(rzh + (size_t)row * 2048 + 1024 + c4);
  const float4 xv = *(const float4*)(x + (size_t)row * 1024 + c4);
  float4 o;
  o.x = (1.f - zv.x) * xv.x + zv.x * hv.x;
  o.y = (1.f - zv.y) * xv.y + zv.y * hv.y;
  o.z = (1.f - zv.z) * xv.z + zv.z * hv.z;
  o.w = (1.f - zv.w) * xv.w + zv.w * hv.w;
  *(float4*)(out + (size_t)row * 1024 + c4) = o;
}

// rx = bf16(r * x) into cat right half (ld 2048); r = rzh cols 0..1023
__global__ __launch_bounds__(256)
void rx_kernel(const float* __restrict__ rzh, const float* __restrict__ x,
               u16* __restrict__ dst)
{
  const int t = blockIdx.x * 256 + threadIdx.x;
  const int row = t >> 8;
  const int c4 = (t & 255) * 4;
  const float4 rv = *(const float4*)(rzh + (size_t)row * 2048 + c4);
  const float4 xv = *(const float4*)(x + (size_t)row * 1024 + c4);
  us4 o;
  o[0] = f2bf(rv.x * xv.x); o[1] = f2bf(rv.y * xv.y);
  o[2] = f2bf(rv.z * xv.z); o[3] = f2bf(rv.w * xv.w);
  *(us4*)(dst + (size_t)row * 2048 + c4) = o;
}

// f32 -> bf16 2D convert with dst leading-dim (src contiguous [rows][2^cshift])
__global__ __launch_bounds__(256)
void cvt2d_kernel(const float* __restrict__ src, u16* __restrict__ dst,
                  int total4, int cshift, int ldd)
{
  const int t = blockIdx.x * 256 + threadIdx.x;
  if (t >= total4) return;
  const int idx = t * 4;
  const int r = idx >> cshift;
  const int c = idx & ((1 << cshift) - 1);
  const float4 v = *(const float4*)(src + (size_t)idx);
  us4 o; o[0] = f2bf(v.x); o[1] = f2bf(v.y); o[2] = f2bf(v.z); o[3] = f2bf(v.w);
  *(us4*)(dst + (size_t)r * ldd + c) = o;
}

__global__ __launch_bounds__(256)
void biasrz_kernel(const float* __restrict__ bg, float* __restrict__ brz)
{
  const int t = blockIdx.x * 256 + threadIdx.x;  // 2048
  brz[t] = (t < 1024) ? 0.f : -bg[t - 1024];
}

// sentinel: unmistakable absmax if workspace is too small
__global__ __launch_bounds__(256)
void sentinel_kernel(float* __restrict__ out, int n)
{
  const int t = blockIdx.x * 256 + threadIdx.x;
  if (t < n) out[t] = 1.0e9f;
}

// ---------------------------------------------------------------------------
// Per-token differential attention over the head axis.
// qkv: [16384][3072] bf16 (q|k|v). out: [16384][1024] bf16 (rmsnorm'ed, scaled).
// One wave per token; 4 tokens / 256-thread block.
// ---------------------------------------------------------------------------
__global__ __launch_bounds__(256)
void attn_kernel(const u16* __restrict__ qkv,
                 const float* __restrict__ lq1, const float* __restrict__ lq2,
                 const float* __restrict__ lk1, const float* __restrict__ lk2,
                 u16* __restrict__ out)
{
  __shared__ float k_s[4][32][36];
  __shared__ float att_s[4][32][33];
  const int wave = threadIdx.x >> 6, lane = threadIdx.x & 63;
  const int tok = blockIdx.x * 4 + wave;
  const u16* qrow = qkv + (size_t)tok * 3072;
  const u16* krow = qrow + 1024;
  const u16* vrow = qrow + 2048;

  // stage K, deinterleaved: k[(ki*16+h)][d] = krow[h*64 + d*2 + ki]
  {
    us8 a = *(const us8*)(krow + lane * 16);
    us8 b = *(const us8*)(krow + lane * 16 + 8);
#pragma unroll
    for (int j = 0; j < 16; ++j) {
      int e = lane * 16 + j;
      u16 usv = (j < 8) ? a[j] : b[j - 8];
      int h = e >> 6, r = e & 63;
      k_s[wave][(r & 1) * 16 + h][r >> 1] = bf2f(usv);
    }
  }
  // q row a = lane&31 into registers (scaled): q[a][d] = qrow[h*64 + d*2 + qi]
  float qr[32];
  {
    const int a = lane & 31, h = a & 15, qi = a >> 4;
#pragma unroll
    for (int s = 0; s < 8; ++s) {
      us8 v8 = *(const us8*)(qrow + h * 64 + s * 8);
#pragma unroll
      for (int u = 0; u < 4; ++u) qr[s * 4 + u] = bf2f(v8[2 * u + qi]) * QSCALE;
    }
  }
  // lambda (scalar)
  float lam;
  {
    const int dd = lane & 31;
    float p1 = lq1[dd] * lk1[dd], p2 = lq2[dd] * lk2[dd];
#pragma unroll
    for (int o = 16; o >= 1; o >>= 1) { p1 += __shfl_xor(p1, o); p2 += __shfl_xor(p2, o); }
    lam = expf(p1) - expf(p2) + LAMBDA0;
  }
  __syncthreads();

  // scores: lane owns row a for cols [bb, bb+16)
  const int a = lane & 31, bb = (lane >> 5) * 16;
  float av[16];
#pragma unroll
  for (int bi = 0; bi < 16; ++bi) {
    const float4* kk = (const float4*)&k_s[wave][bb + bi][0];
    float s = 0.f;
#pragma unroll
    for (int d4 = 0; d4 < 8; ++d4) {
      float4 kv = kk[d4];
      s += qr[d4 * 4 + 0] * kv.x + qr[d4 * 4 + 1] * kv.y +
           qr[d4 * 4 + 2] * kv.z + qr[d4 * 4 + 3] * kv.w;
    }
    av[bi] = s;
  }
  // softmax across the 32-wide row (2 lanes per row)
  float mx = av[0];
#pragma unroll
  for (int i = 1; i < 16; ++i) mx = fmaxf(mx, av[i]);
  mx = fmaxf(mx, __shfl_xor(mx, 32));
  float se = 0.f;
#pragma unroll
  for (int i = 0; i < 16; ++i) { av[i] = expf(av[i] - mx); se += av[i]; }
  se += __shfl_xor(se, 32);
  const float inv = 1.f / se;
#pragma unroll
  for (int i = 0; i < 16; ++i) att_s[wave][a][bb + i] = av[i] * inv;
  __syncthreads();

  // PV: lane owns out row a2 = lane>>2, cols [jb, jb+16)
  const int a2 = lane >> 2, jb = (lane & 3) * 16;
  float o[16];
#pragma unroll
  for (int j = 0; j < 16; ++j) o[j] = 0.f;
#pragma unroll
  for (int h = 0; h < 16; ++h) {
    const float dc = att_s[wave][a2][h] - lam * att_s[wave][16 + a2][16 + h];
    const u16* vv = vrow + h * 64 + jb;
    us8 v0 = *(const us8*)vv;
    us8 v1 = *(const us8*)(vv + 8);
#pragma unroll
    for (int j = 0; j < 8; ++j) { o[j] += dc * bf2f(v0[j]); o[8 + j] += dc * bf2f(v1[j]); }
  }
  // rmsnorm over 64 (4-lane group) + (1-lambda_init)
  float ss = 0.f;
#pragma unroll
  for (int j = 0; j < 16; ++j) ss += o[j] * o[j];
  ss += __shfl_xor(ss, 1);
  ss += __shfl_xor(ss, 2);
  const float sc = rsqrtf(ss * (1.f / 64.f) + 1e-5f) * ONE_MINUS_LAMBDA0;
  us8 r0, r1;
#pragma unroll
  for (int j = 0; j < 8; ++j) { r0[j] = f2bf(o[j] * sc); r1[j] = f2bf(o[8 + j] * sc); }
  u16* op = out + (size_t)tok * 1024 + a2 * 64 + jb;
  *(us8*)op = r0;
  *(us8*)(op + 8) = r1;
}

// ---------------------------------------------------------------------------
// Workspace layout (bytes), 228 MiB total. Liveness-based aliasing:
//  R1 (128 MiB): qkv bf16 [16384][3072] + {s, attn_out} bf16 at +96MiB
//                -> rzh f32 [16384][2048] (z cols 1024.., h overwrites r cols)
//                -> f1 bf16 [16384][4096] -> rzh2 f32
//  CAT (64 MiB): [y|x] -> [y|r*x] -> [c|conn_bf] -> [y2|conn_bf] -> [y2|r*conn]
//  conn f32 lives in d_out (combine2 updates it in place).
// ---------------------------------------------------------------------------
enum : size_t {
  OFF_WQKV = 0,
  OFF_WO   = OFF_WQKV + (size_t)3072 * 1024 * 2,
  OFF_WRZ  = OFF_WO   + (size_t)1024 * 1024 * 2,
  OFF_WG   = OFF_WRZ  + (size_t)2048 * 2048 * 2,
  OFF_W1   = OFF_WG   + (size_t)1024 * 2048 * 2,
  OFF_W2   = OFF_W1   + (size_t)4096 * 1024 * 2,
  OFF_BRZ  = OFF_W2   + (size_t)1024 * 4096 * 2,
  OFF_R1   = OFF_BRZ  + (size_t)2048 * 4,
  OFF_CAT  = OFF_R1   + (size_t)134217728,
  WS_NEED  = OFF_CAT  + (size_t)16384 * 2048 * 2
};

extern "C" void kernel_launch(void* const* d_in, const int* in_sizes, int n_in,
                              void* d_out, int out_size, void* d_ws, size_t ws_size,
                              hipStream_t stream)
{
  (void)in_sizes; (void)n_in;
  if (ws_size < WS_NEED) {   // unmistakable failure signature (absmax ~1e9)
    sentinel_kernel<<<(out_size + 255) / 256, 256, 0, stream>>>((float*)d_out, out_size);
    return;
  }

  const float* src  = (const float*)d_in[0];
  const float* Wq   = (const float*)d_in[1];
  const float* Wk   = (const float*)d_in[2];
  const float* Wv   = (const float*)d_in[3];
  const float* Wo   = (const float*)d_in[4];
  const float* bo   = (const float*)d_in[5];
  const float* lq1  = (const float*)d_in[6];
  const float* lq2  = (const float*)d_in[7];
  const float* lk1  = (const float*)d_in[8];
  const float* lk2  = (const float*)d_in[9];
  const float* ln1g = (const float*)d_in[10];
  const float* ln1b = (const float*)d_in[11];
  const float* ln2g = (const float*)d_in[12];
  const float* ln2b = (const float*)d_in[13];
  const float* W1   = (const float*)d_in[14];
  const float* b1   = (const float*)d_in[15];
  const float* W2   = (const float*)d_in[16];
  const float* b2   = (const float*)d_in[17];
  const float* Wr   = (const float*)d_in[18];
  const float* Ur   = (const float*)d_in[19];
  const float* Wz   = (const float*)d_in[20];
  const float* Uz   = (const float*)d_in[21];
  const float* Wg   = (const float*)d_in[22];
  const float* Ug   = (const float*)d_in[23];
  const float* bg   = (const float*)d_in[24];

  char* ws = (char*)d_ws;
  u16*   wqkv = (u16*)(ws + OFF_WQKV);
  u16*   wo_b = (u16*)(ws + OFF_WO);
  u16*   wrz  = (u16*)(ws + OFF_WRZ);
  u16*   wgc  = (u16*)(ws + OFF_WG);
  u16*   w1b  = (u16*)(ws + OFF_W1);
  u16*   w2b  = (u16*)(ws + OFF_W2);
  float* brz  = (float*)(ws + OFF_BRZ);
  u16*   r1u  = (u16*)(ws + OFF_R1);                 // qkv bf16 / f1 bf16
  u16*   sbuf = (u16*)(ws + OFF_R1 + 100663296);     // s / attn_out (R1+96MiB)
  float* rzh  = (float*)(ws + OFF_R1);               // rz/h f32 (aliases r1u)
  u16*   cat  = (u16*)(ws + OFF_CAT);                // [left | right], ld 2048
  float* conn = (float*)d_out;                       // conn lives in d_out

  auto cvt = [&](const float* s, u16* dst, int rows, int cshift, int ldd) {
    int total4 = (rows << cshift) >> 2;
    cvt2d_kernel<<<(total4 + 255) / 256, 256, 0, stream>>>(s, dst, total4, cshift, ldd);
  };

  // ---- weight prep (bf16, concatenated layouts) ----
  cvt(Wq, wqkv,                     1024, 10, 1024);
  cvt(Wk, wqkv + 1024 * 1024,       1024, 10, 1024);
  cvt(Wv, wqkv + 2 * 1024 * 1024,   1024, 10, 1024);
  cvt(Wo, wo_b,                     1024, 10, 1024);
  cvt(Wr, wrz,                      1024, 10, 2048);
  cvt(Ur, wrz + 1024,               1024, 10, 2048);
  cvt(Wz, wrz + 2048 * 1024,        1024, 10, 2048);
  cvt(Uz, wrz + 2048 * 1024 + 1024, 1024, 10, 2048);
  cvt(Wg, wgc,                      1024, 10, 2048);
  cvt(Ug, wgc + 1024,               1024, 10, 2048);
  cvt(W1, w1b,                      4096, 10, 1024);
  cvt(W2, w2b,                      1024, 12, 4096);
  cvt(src, cat + 1024,             16384, 10, 2048);   // x half of cat for GRU1
  biasrz_kernel<<<8, 256, 0, stream>>>(bg, brz);

  // ---- s = LN1(src) -> R1+96MiB ----
  ln_kernel<<<16384, 256, 0, stream>>>(src, ln1g, ln1b, sbuf);

  // ---- QKV fused GEMM -> R1[0:96MiB] [16384][3072] bf16 ----
  gemm256<0, 1><<<dim3(12, 64), 512, 0, stream>>>(sbuf, 1024, wqkv, nullptr, r1u, 3072, 1024);

  // ---- per-token differential attention -> R1+96MiB (over s, now dead) ----
  attn_kernel<<<4096, 256, 0, stream>>>(r1u, lq1, lq2, lk1, lk2, sbuf);

  // ---- y = relu(attn_out @ Wo.T + bo) -> cat left ----
  gemm256<1, 1><<<dim3(4, 64), 512, 0, stream>>>(sbuf, 1024, wo_b, bo, cat, 2048, 1024);

  // ---- GRU1 ----
  // [r|z] = sigmoid([y|x] @ [Wr|Ur;Wz|Uz].T + [0|-bg]) -> rzh f32 (qkv dead)
  gemm256<2, 0><<<dim3(8, 64), 512, 0, stream>>>(cat, 2048, wrz, brz, rzh, 2048, 2048);
  rx_kernel<<<16384, 256, 0, stream>>>(rzh, src, cat + 1024);            // r*x
  // h = tanh([y|r*x] @ [Wg|Ug].T) -> rzh cols 0..1023 (over r, now dead)
  gemm256<3, 0><<<dim3(4, 64), 512, 0, stream>>>(cat, 2048, wgc, nullptr, rzh, 2048, 2048);
  // conn = (1-z)src + z*h -> d_out ; c = LN2(conn) -> cat left ; conn_bf -> cat right
  combine_ln_kernel<<<16384, 256, 0, stream>>>(src, rzh, ln2g, ln2b, conn, cat);

  // ---- FFN: f1 = relu(c@W1.T+b1) -> R1 (rzh dead); y2 = relu(f1@W2.T+b2) -> cat left
  gemm256<1, 1><<<dim3(16, 64), 512, 0, stream>>>(cat, 2048, w1b, b1, r1u, 4096, 1024);
  gemm256<1, 1><<<dim3(4, 64), 512, 0, stream>>>(r1u, 4096, w2b, b2, cat, 2048, 4096);

  // ---- GRU2 ----
  gemm256<2, 0><<<dim3(8, 64), 512, 0, stream>>>(cat, 2048, wrz, brz, rzh, 2048, 2048);
  rx_kernel<<<16384, 256, 0, stream>>>(rzh, conn, cat + 1024);           // r*conn
  gemm256<3, 0><<<dim3(4, 64), 512, 0, stream>>>(cat, 2048, wgc, nullptr, rzh, 2048, 2048);
  combine2_kernel<<<16384, 256, 0, stream>>>(conn, rzh, (float*)d_out);
}